// Round 3
// baseline (761.781 us; speedup 1.0000x reference)
//
#include <hip/hip_runtime.h>
#include <hip/hip_fp16.h>

#define NS 576          // samples per ray (384 inner + 192 outer)
#define RAYS_PER_BLOCK 4

typedef float vfloat4 __attribute__((ext_vector_type(4)));   // native clang vector: OK for nontemporal builtins

__global__ __launch_bounds__(256) void nerf_render_kernel(
    const float* __restrict__ sigmas,   // [N, S]
    const float* __restrict__ rgbs,     // [N, S, 3]
    const float* __restrict__ bg,       // [3]
    float* __restrict__ img,            // [N, 3]
    float* __restrict__ invd,           // [N]
    float* __restrict__ wout,           // [N, S]
    float* __restrict__ zlout,          // [N, S]
    int N)
{
    __shared__ __align__(16) float s_z[NS];
    __shared__ __align__(16) float s_delta[NS];
    __shared__ __align__(16) float s_invz[NS];
    __shared__ __align__(16) float s_zlog[NS];

    const int tid = threadIdx.x;

    // ---- Build z tables once per block (matches jnp.linspace / 10**x / fp16 round-trip) ----
    for (int s = tid; s < NS; s += 256) {
        float zl;
        if (s < 384) {
            const float start = (float)(-1.3010299956639813);            // log10(0.05)
            const float stop  = (float)(-1.3010299956639813 / 384.0);    // a/384
            const float step  = (stop - start) / 383.0f;
            zl = start + (float)s * step;
        } else {
            const float stop = (float)(2.0 - 2.0 / 192.0);               // 1.98958333...
            const float step = stop / 191.0f;
            zl = (float)(s - 384) * step;
        }
        // z_vals = fp32(fp16(10^zl))  (reference quantizes z_vals to fp16)
        float z = __half2float(__float2half_rn(exp10f(zl)));
        s_zlog[s] = zl;
        s_z[s]    = z;
    }
    __syncthreads();
    for (int s = tid; s < NS; s += 256) {
        float z = s_z[s];
        s_delta[s] = (s == NS - 1) ? 1e10f : (s_z[s + 1] - z);
        s_invz[s]  = 1.0f / z;
    }
    __syncthreads();

    const int wave = tid >> 6;
    const int lane = tid & 63;
    const int ray  = blockIdx.x * RAYS_PER_BLOCK + wave;
    if (ray >= N) return;

    const float* __restrict__ sig = sigmas + (size_t)ray * NS;
    const float* __restrict__ rgb = rgbs   + (size_t)ray * NS * 3;
    float* __restrict__ wrow = wout  + (size_t)ray * NS;
    float* __restrict__ zrow = zlout + (size_t)ray * NS;

    // ---- z_vals_log output: pure broadcast of the table; coalesced float4 stores ----
    {
        const vfloat4* zl4 = reinterpret_cast<const vfloat4*>(s_zlog);
        vfloat4* zr4 = reinterpret_cast<vfloat4*>(zrow);
        #pragma unroll
        for (int i = 0; i < 3; ++i) {
            const int idx = lane + 64 * i;          // 144 vfloat4 per row
            if (idx < NS / 4)
                __builtin_nontemporal_store(zl4[idx], zr4 + idx);
        }
    }

    float T = 1.0f;                    // running exclusive transmittance carry
    float a0 = 0.f, a1 = 0.f, a2 = 0.f;
    float id = 0.f, wsum = 0.f;

    // ---- chunks 0/1: 256 samples each, 4 consecutive samples per lane ----
    // All global accesses are aligned 16B: sigma 1x dwordx4, rgb 3x dwordx4, w 1x dwordx4.
    #pragma unroll
    for (int c = 0; c < 2; ++c) {
        const int s0 = c * 256 + lane * 4;

        const vfloat4 sg = *reinterpret_cast<const vfloat4*>(sig + s0);
        const vfloat4 rA = *reinterpret_cast<const vfloat4*>(rgb + 3 * s0);      // r0 g0 b0 r1
        const vfloat4 rB = *reinterpret_cast<const vfloat4*>(rgb + 3 * s0 + 4);  // g1 b1 r2 g2
        const vfloat4 rC = *reinterpret_cast<const vfloat4*>(rgb + 3 * s0 + 8);  // b2 r3 g3 b3
        const vfloat4 dv = *reinterpret_cast<const vfloat4*>(&s_delta[s0]);
        const vfloat4 iv = *reinterpret_cast<const vfloat4*>(&s_invz[s0]);

        const float e0 = expf(-sg.x * dv.x);
        const float e1 = expf(-sg.y * dv.y);
        const float e2 = expf(-sg.z * dv.z);
        const float e3 = expf(-sg.w * dv.w);
        const float P0 = e0 + 1e-10f;              // (1 - alpha + eps)
        const float P1 = e1 + 1e-10f;
        const float P2 = e2 + 1e-10f;
        const float P3 = e3 + 1e-10f;

        // per-lane product, then a single 64-lane inclusive scan per 256 samples
        float sc = ((P0 * P1) * P2) * P3;
        #pragma unroll
        for (int off = 1; off < 64; off <<= 1) {
            float v = __shfl_up(sc, off);
            if (lane >= off) sc *= v;
        }
        const float prev = __shfl_up(sc, 1);
        const float ex = (lane == 0) ? T : T * prev;   // exclusive transmittance at sample s0

        const float al0 = 1.0f - e0;
        const float al1 = 1.0f - e1;
        const float al2 = 1.0f - e2;
        const float al3 = 1.0f - e3;

        const float w0 = al0 * ex;
        const float t1 = ex * P0;
        const float w1 = al1 * t1;
        const float t2 = t1 * P1;
        const float w2 = al2 * t2;
        const float t3 = t2 * P2;
        const float w3 = al3 * t3;

        vfloat4 wv; wv.x = w0; wv.y = w1; wv.z = w2; wv.w = w3;
        __builtin_nontemporal_store(wv, reinterpret_cast<vfloat4*>(wrow + s0));

        a0 = fmaf(w0, rA.x, a0); a0 = fmaf(w1, rA.w, a0); a0 = fmaf(w2, rB.z, a0); a0 = fmaf(w3, rC.y, a0);
        a1 = fmaf(w0, rA.y, a1); a1 = fmaf(w1, rB.x, a1); a1 = fmaf(w2, rB.w, a1); a1 = fmaf(w3, rC.z, a1);
        a2 = fmaf(w0, rA.z, a2); a2 = fmaf(w1, rB.y, a2); a2 = fmaf(w2, rC.x, a2); a2 = fmaf(w3, rC.w, a2);
        id = fmaf(w0, iv.x, id); id = fmaf(w1, iv.y, id); id = fmaf(w2, iv.z, id); id = fmaf(w3, iv.w, id);
        wsum += (w0 + w1) + (w2 + w3);

        T *= __shfl(sc, 63);           // carry product of all 256 P's
    }

    // ---- chunk 2: samples 512..575, one per lane (classic path) ----
    {
        const int s = 512 + lane;
        const float sigma = sig[s];
        const float delta = s_delta[s];
        const float e     = expf(-sigma * delta);
        const float alpha = 1.0f - e;
        float P = e + 1e-10f;
        #pragma unroll
        for (int off = 1; off < 64; off <<= 1) {
            float v = __shfl_up(P, off);
            if (lane >= off) P *= v;
        }
        const float prev = __shfl_up(P, 1);
        const float ex   = (lane == 0) ? T : T * prev;
        const float w    = alpha * ex;

        __builtin_nontemporal_store(w, wrow + s);

        const float r0 = rgb[3 * s + 0];
        const float r1 = rgb[3 * s + 1];
        const float r2 = rgb[3 * s + 2];
        a0 = fmaf(w, r0, a0);
        a1 = fmaf(w, r1, a1);
        a2 = fmaf(w, r2, a2);
        id = fmaf(w, s_invz[s], id);
        wsum += w;
    }

    // wave-level reductions
    #pragma unroll
    for (int off = 32; off > 0; off >>= 1) {
        a0   += __shfl_down(a0, off);
        a1   += __shfl_down(a1, off);
        a2   += __shfl_down(a2, off);
        id   += __shfl_down(id, off);
        wsum += __shfl_down(wsum, off);
    }

    if (lane == 0) {
        const float rem = 1.0f - wsum;
        img[(size_t)ray * 3 + 0] = fmaf(rem, bg[0], a0);
        img[(size_t)ray * 3 + 1] = fmaf(rem, bg[1], a1);
        img[(size_t)ray * 3 + 2] = fmaf(rem, bg[2], a2);
        invd[ray] = id;
    }
}

extern "C" void kernel_launch(void* const* d_in, const int* in_sizes, int n_in,
                              void* d_out, int out_size, void* d_ws, size_t ws_size,
                              hipStream_t stream) {
    // inputs: rays_o [N,3], rays_d [N,3], bg_color [3], sigmas [N,S], rgbs [N,S,3]
    const int N = in_sizes[0] / 3;
    const float* sigmas = (const float*)d_in[3];
    const float* rgbs   = (const float*)d_in[4];
    const float* bg     = (const float*)d_in[2];

    // outputs concatenated: image [N,3], invdepth [N], weights [N,S], z_vals_log [N,S]
    float* out   = (float*)d_out;
    float* img   = out;
    float* invd  = out + (size_t)3 * N;
    float* wout  = out + (size_t)4 * N;
    float* zlout = out + (size_t)4 * N + (size_t)N * NS;

    const int blocks = (N + RAYS_PER_BLOCK - 1) / RAYS_PER_BLOCK;
    nerf_render_kernel<<<blocks, 256, 0, stream>>>(sigmas, rgbs, bg, img, invd,
                                                   wout, zlout, N);
}